// Round 9
// baseline (1697.902 us; speedup 1.0000x reference)
//
#include <hip/hip_runtime.h>
#include <hip/hip_fp16.h>

typedef __attribute__((ext_vector_type(8))) short short8;
typedef __attribute__((ext_vector_type(4))) float f32x4;
typedef __attribute__((ext_vector_type(2))) unsigned int u32x2;

__device__ __forceinline__ unsigned short bf16_of(float f) {
    unsigned u = __builtin_bit_cast(unsigned, f);
    u += 0x7fffu + ((u >> 16) & 1u);   // RNE
    return (unsigned short)(u >> 16);
}
__device__ __forceinline__ unsigned bf16pk(float a, float b) {
    return (unsigned)bf16_of(a) | ((unsigned)bf16_of(b) << 16);
}
// fp16 pack (RTZ) / unpack for the xw streams.
__device__ __forceinline__ unsigned fp16pk(float a, float b) {
    return __builtin_bit_cast(unsigned, __builtin_amdgcn_cvt_pkrtz(a, b));
}
__device__ __forceinline__ f32x4 h4f(u32x2 v) {
    __half2 a = __builtin_bit_cast(__half2, v[0]);
    __half2 b = __builtin_bit_cast(__half2, v[1]);
    float2 fa = __half22float2(a), fb = __half22float2(b);
    f32x4 r; r[0] = fa.x; r[1] = fa.y; r[2] = fb.x; r[3] = fb.y;
    return r;
}
__device__ __forceinline__ float fexp2(float x) { return __builtin_amdgcn_exp2f(x); }
__device__ __forceinline__ float frcp(float x) { return __builtin_amdgcn_rcpf(x); }
__device__ __forceinline__ float sigm(float x) { return frcp(1.f + fexp2(-1.44269504f * x)); }
__device__ __forceinline__ f32x4 mfma16(short8 a, short8 b, f32x4 c) {
    return __builtin_amdgcn_mfma_f32_16x16x32_bf16(a, b, c, 0, 0, 0);
}
// DPP cross-lane within 16-lane rows. row_shr:8 -> lane i gets lane i-8;
// row_shl:8 -> lane i gets lane i+8 (bound_ctrl: OOB reads 0).
__device__ __forceinline__ float dpp_shr8(float x) {
    return __builtin_bit_cast(float, __builtin_amdgcn_update_dpp(
        0, __builtin_bit_cast(int, x), 0x118, 0xF, 0xF, true));
}
__device__ __forceinline__ float dpp_shl8(float x) {
    return __builtin_bit_cast(float, __builtin_amdgcn_update_dpp(
        0, __builtin_bit_cast(int, x), 0x108, 0xF, 0xF, true));
}

struct PrepArgs {
    const float* src[8];
    unsigned short* dst[8];
    int N[8];
};

// ---------------------------------------------------------------------------
// Fused-GNN shared memory (gemm and agg roles share one 17.4 KB union so
// 5+ blocks/CU stay co-resident -> flag waits can never deadlock).
union SmemF {
    struct { float As[32][33]; float Bs[32][68]; unsigned short T[32][70]; } g;
    struct { unsigned short Alds[32 * 40]; unsigned short Blds[128 * 40]; float sjL[1024]; } a;
};

// flag helpers: proven agent-scope acquire/release pattern (same as lstm_pipe)
__device__ __forceinline__ void waitflag(int* p, int target, int tid) {
    if (tid == 0) {
        while (__hip_atomic_load(p, __ATOMIC_ACQUIRE, __HIP_MEMORY_SCOPE_AGENT) < target)
            __builtin_amdgcn_s_sleep(4);
    }
    __syncthreads();   // wave-0's acquire covers the CU's L1; others just barrier
}
__device__ __forceinline__ void pubflag(int* p, int tid) {
    __syncthreads();   // drains all waves' global stores (vmcnt0 before barrier)
    if (tid == 0)
        __hip_atomic_fetch_add(p, 1, __ATOMIC_RELEASE, __HIP_MEMORY_SCOPE_AGENT);
}

// ---------------------------------------------------------------------------
// GNN linear tile: h = A @ W + b (fp32, N=128), 32-row M-tile (bx,by),
// emitting bf16 hT[b][d][node] + si/sj partial attention dots.
__device__ void gemm_dev(
    const float* __restrict__ A, const float* __restrict__ B,
    const float* __restrict__ bias, const float* __restrict__ aW,
    unsigned short* __restrict__ hT, float* __restrict__ siP,
    float* __restrict__ sjP, int K, int bx, int by, int tid, SmemF* sm)
{
    float (*As)[33] = sm->g.As;
    float (*Bs)[68] = sm->g.Bs;
    unsigned short (*T)[70] = sm->g.T;
    const int tx = tid & 15, ty = tid >> 4;
    const int m0 = by * 32, n0 = bx * 64;
    float acc[2][4];
#pragma unroll
    for (int i = 0; i < 2; ++i)
#pragma unroll
        for (int j = 0; j < 4; ++j) acc[i][j] = 0.f;

    for (int k0 = 0; k0 < K; k0 += 32) {
        __syncthreads();
        {   // stage A 32x32
            const int r = tid >> 3, kk = (tid & 7) * 4;
            f32x4 v = *(const f32x4*)(A + (size_t)(m0 + r) * K + k0 + kk);
#pragma unroll
            for (int e = 0; e < 4; ++e) As[r][kk + e] = v[e];
        }
        {   // stage B 32x64 (B is [K][128])
            const int kk = tid >> 3, nn = (tid & 7) * 8;
            const float* src = B + (size_t)(k0 + kk) * 128 + n0 + nn;
            f32x4 v0 = *(const f32x4*)src;
            f32x4 v1 = *(const f32x4*)(src + 4);
#pragma unroll
            for (int e = 0; e < 4; ++e) { Bs[kk][nn + e] = v0[e]; Bs[kk][nn + 4 + e] = v1[e]; }
        }
        __syncthreads();
#pragma unroll 8
        for (int k = 0; k < 32; ++k) {
            float a0 = As[ty * 2 + 0][k], a1 = As[ty * 2 + 1][k];
            f32x4 bv = *(const f32x4*)&Bs[k][tx * 4];
#pragma unroll
            for (int j = 0; j < 4; ++j) {
                acc[0][j] += a0 * bv[j];
                acc[1][j] += a1 * bv[j];
            }
        }
    }
    // bias
    f32x4 bv = *(const f32x4*)&bias[n0 + tx * 4];
#pragma unroll
    for (int i = 0; i < 2; ++i)
#pragma unroll
        for (int j = 0; j < 4; ++j) acc[i][j] += bv[j];

    // si/sj partial dots over this block's 64 cols.
    f32x4 wj = *(const f32x4*)&aW[n0 + tx * 4];
    f32x4 wi = *(const f32x4*)&aW[128 + n0 + tx * 4];
#pragma unroll
    for (int i = 0; i < 2; ++i) {
        float pj = acc[i][0] * wj[0] + acc[i][1] * wj[1] + acc[i][2] * wj[2] + acc[i][3] * wj[3];
        float pi = acc[i][0] * wi[0] + acc[i][1] * wi[1] + acc[i][2] * wi[2] + acc[i][3] * wi[3];
#pragma unroll
        for (int o = 8; o > 0; o >>= 1) {
            pj += __shfl_xor(pj, o);
            pi += __shfl_xor(pi, o);
        }
        if (tx == 0) {
            const int m = m0 + ty * 2 + i;
            sjP[bx * 8192 + m] = pj;
            siP[bx * 8192 + m] = pi;
        }
    }

    // bf16 transpose via LDS -> hT[b][n0+d][node]
#pragma unroll
    for (int i = 0; i < 2; ++i) {
        unsigned* tp = (unsigned*)&T[ty * 2 + i][tx * 4];
        tp[0] = bf16pk(acc[i][0], acc[i][1]);
        tp[1] = bf16pk(acc[i][2], acc[i][3]);
    }
    __syncthreads();
    const int b = m0 >> 10, node0 = m0 & 1023;
    const int dr = tid >> 4, npair = tid & 15;
#pragma unroll
    for (int rr = 0; rr < 4; ++rr) {
        const int d = rr * 16 + dr;
        unsigned o = (unsigned)T[npair * 2][d] | ((unsigned)T[npair * 2 + 1][d] << 16);
        *(unsigned*)(hT + ((size_t)b * 128 + n0 + d) * 1024 + node0 + npair * 2) = o;
    }
}

// ---------------------------------------------------------------------------
// GNN aggregate tile: out[b,i,d] = sum_j sigmoid(si+sj+ab)*adj*h, 32-row
// i-tile (it,b); depth-2 register prefetch of adj/hT.
__device__ void agg_dev(
    const float* __restrict__ adj, const unsigned short* __restrict__ hT,
    const float* __restrict__ siP, const float* __restrict__ sjP,
    const float* __restrict__ abp, float* __restrict__ out, int RELU,
    int it, int b, int tid, SmemF* sm)
{
    unsigned short* Alds = sm->a.Alds;
    unsigned short* Blds = sm->a.Blds;
    float* sjL = sm->a.sjL;
    const int i0 = it * 32;
    const int lane = tid & 63, w = tid >> 6;
    const int quad = lane >> 4, col = lane & 15;
    const int rh = w & 1, nh = w >> 1;   // wave -> (i-half, d-half)
    const float ab = abp[0];
    const float* adjb = adj + (size_t)b * 1024 * 1024;
    const unsigned short* hTb = hT + (size_t)b * 128 * 1024;

    for (int j = tid; j < 1024; j += 256)
        sjL[j] = sjP[b * 1024 + j] + sjP[8192 + b * 1024 + j];

    const int ar_ = tid >> 3, ash = (tid & 7) * 4;   // A-stage: 32 rows x 8 thr x 4 j
    const int br_ = tid >> 1, bsh = (tid & 1) * 16;  // B-stage: 128 rows x 2 thr x 16 j
    const float sii = siP[b * 1024 + i0 + ar_] + siP[8192 + b * 1024 + i0 + ar_] + ab;

    const float* aptr = adjb + (size_t)(i0 + ar_) * 1024 + ash;
    const unsigned short* bptr = hTb + (size_t)br_ * 1024 + bsh;

    f32x4 paA = *(const f32x4*)(aptr);
    short8 pbA0 = *(const short8*)(bptr);
    short8 pbA1 = *(const short8*)(bptr + 8);
    f32x4 paB = *(const f32x4*)(aptr + 32);
    short8 pbB0 = *(const short8*)(bptr + 32);
    short8 pbB1 = *(const short8*)(bptr + 40);

    f32x4 acc[4] = {};

    for (int j0 = 0; j0 < 1024; j0 += 64) {
        // ---- phase A: tile j0
        __syncthreads();
        {
            float s0 = sigm(sii + sjL[j0 + ash + 0]) * paA[0];
            float s1 = sigm(sii + sjL[j0 + ash + 1]) * paA[1];
            float s2 = sigm(sii + sjL[j0 + ash + 2]) * paA[2];
            float s3 = sigm(sii + sjL[j0 + ash + 3]) * paA[3];
            u32x2 o = {bf16pk(s0, s1), bf16pk(s2, s3)};
            *(u32x2*)&Alds[ar_ * 40 + ash] = o;
            *(short8*)&Blds[br_ * 40 + bsh] = pbA0;
            *(short8*)&Blds[br_ * 40 + bsh + 8] = pbA1;
        }
        if (j0 + 64 < 1024) {
            paA = *(const f32x4*)(aptr + j0 + 64);
            pbA0 = *(const short8*)(bptr + j0 + 64);
            pbA1 = *(const short8*)(bptr + j0 + 72);
        }
        __syncthreads();
        {
            short8 af = *(const short8*)&Alds[(rh * 16 + col) * 40 + quad * 8];
#pragma unroll
            for (int nt = 0; nt < 4; ++nt) {
                short8 bf = *(const short8*)&Blds[((nh * 4 + nt) * 16 + col) * 40 + quad * 8];
                acc[nt] = mfma16(af, bf, acc[nt]);
            }
        }
        // ---- phase B: tile j0+32
        __syncthreads();
        {
            float s0 = sigm(sii + sjL[j0 + 32 + ash + 0]) * paB[0];
            float s1 = sigm(sii + sjL[j0 + 32 + ash + 1]) * paB[1];
            float s2 = sigm(sii + sjL[j0 + 32 + ash + 2]) * paB[2];
            float s3 = sigm(sii + sjL[j0 + 32 + ash + 3]) * paB[3];
            u32x2 o = {bf16pk(s0, s1), bf16pk(s2, s3)};
            *(u32x2*)&Alds[ar_ * 40 + ash] = o;
            *(short8*)&Blds[br_ * 40 + bsh] = pbB0;
            *(short8*)&Blds[br_ * 40 + bsh + 8] = pbB1;
        }
        if (j0 + 96 < 1024) {
            paB = *(const f32x4*)(aptr + j0 + 96);
            pbB0 = *(const short8*)(bptr + j0 + 96);
            pbB1 = *(const short8*)(bptr + j0 + 104);
        }
        __syncthreads();
        {
            short8 af = *(const short8*)&Alds[(rh * 16 + col) * 40 + quad * 8];
#pragma unroll
            for (int nt = 0; nt < 4; ++nt) {
                short8 bf = *(const short8*)&Blds[((nh * 4 + nt) * 16 + col) * 40 + quad * 8];
                acc[nt] = mfma16(af, bf, acc[nt]);
            }
        }
    }
    const int ibase = i0 + rh * 16 + quad * 4;
#pragma unroll
    for (int nt = 0; nt < 4; ++nt) {
        const int d = (nh * 4 + nt) * 16 + col;
#pragma unroll
        for (int r = 0; r < 4; ++r) {
            float v = acc[nt][r];
            if (RELU) v = fmaxf(v, 0.f);
            out[((size_t)b * 1024 + ibase + r) * 128 + d] = v;
        }
    }
}

// ---------------------------------------------------------------------------
struct GnnArgs {
    const float* nf; const float* adj;
    const float* gW0; const float* gb0; const float* gaW0; const float* gab0;
    const float* gW1; const float* gb1; const float* gaW1; const float* gab1;
    const float* gW2; const float* gb2; const float* gaW2; const float* gab2;
    float* bufX; float* bufH3;
    unsigned short* hT0; unsigned short* hT1;
    float* siP0; float* sjP0; float* siP1; float* sjP1;
    int* gf;                     // fg1[8] fa1[256] fg2[8] fa2[256] fg3[8]
    const float* wih; unsigned short* wihB;
    PrepArgs prep;
};

// Fused GNN front-end: 6 former dispatches as 2 launches with per-tile flag
// dependencies (gemm tile (bx,by) of layer l+1 waits exactly on agg tile by
// of layer l; agg tile (it,b) waits the 64 gemm blocks of batch b).
// __launch_bounds__(256,5) caps VGPR<=102 -> >=5 blocks/CU (LDS 17.4KB -> 9),
// so phase-0's 1280 blocks are ALL co-resident: spin-waits cannot deadlock.
__global__ __launch_bounds__(256, 5) void gnn_fused(GnnArgs a, int phase)
{
    __shared__ __align__(16) SmemF sm;
    const int bid = blockIdx.x, tid = threadIdx.x;
    int* fg1 = a.gf;
    int* fa1 = a.gf + 8;
    int* fg2 = a.gf + 264;
    int* fa2 = a.gf + 272;
    int* fg3 = a.gf + 528;

    if (phase == 0) {
        if (bid < 512) {                       // layer-1 linear (K=64)
            const int bx = bid & 1, by = bid >> 1;
            gemm_dev(a.nf, a.gW0, a.gb0, a.gaW0, a.hT0, a.siP0, a.sjP0, 64,
                     bx, by, tid, &sm);
            pubflag(&fg1[by >> 5], tid);
        } else if (bid < 768) {                // layer-1 aggregate (relu)
            const int idx = bid - 512, it = idx & 31, b = idx >> 5;
            waitflag(&fg1[b], 64, tid);
            agg_dev(a.adj, a.hT0, a.siP0, a.sjP0, a.gab0, a.bufX, 1, it, b, tid, &sm);
            pubflag(&fa1[idx], tid);
        } else {                               // layer-2 linear (K=128)
            const int idx = bid - 768, bx = idx & 1, by = idx >> 1;
            waitflag(&fa1[by], 1, tid);
            gemm_dev(a.bufX, a.gW1, a.gb1, a.gaW1, a.hT1, a.siP1, a.sjP1, 128,
                     bx, by, tid, &sm);
            pubflag(&fg2[by >> 5], tid);
        }
    } else {
        if (bid < 256) {                       // layer-2 aggregate (relu)
            const int it = bid & 31, b = bid >> 5;
            waitflag(&fg2[b], 64, tid);
            agg_dev(a.adj, a.hT1, a.siP1, a.sjP1, a.gab1, a.bufX, 1, it, b, tid, &sm);
            pubflag(&fa2[bid], tid);
        } else if (bid < 768) {                // layer-3 linear (K=128)
            const int idx = bid - 256, bx = idx & 1, by = idx >> 1;
            waitflag(&fa2[by], 1, tid);
            gemm_dev(a.bufX, a.gW2, a.gb2, a.gaW2, a.hT0, a.siP0, a.sjP0, 128,
                     bx, by, tid, &sm);
            pubflag(&fg3[by >> 5], tid);
        } else if (bid < 1024) {               // layer-3 aggregate (no relu)
            const int idx = bid - 768, it = idx & 31, b = idx >> 5;
            waitflag(&fg3[b], 64, tid);
            agg_dev(a.adj, a.hT0, a.siP0, a.sjP0, a.gab2, a.bufH3, 0, it, b, tid, &sm);
        } else {                               // prep tails (no deps)
            const int pid = bid - 1024;        // 0..11
            if (pid < 8) {
                const float* src = a.prep.src[pid];
                unsigned short* dst = a.prep.dst[pid];
                const int N = a.prep.N[pid];
                const int n0 = tid >> 4, kc = (tid & 15) * 8;
                for (int n = n0; n < N; n += 16) {
                    unsigned o[4];
#pragma unroll
                    for (int e = 0; e < 8; e += 2)
                        o[e >> 1] = bf16pk(src[(size_t)(kc + e) * N + n],
                                           src[(size_t)(kc + e + 1) * N + n]);
                    *(u32x2*)&dst[n * 128 + kc] = *(u32x2*)&o[0];
                    *(u32x2*)&dst[n * 128 + kc + 4] = *(u32x2*)&o[2];
                }
            } else {
                // l0Wih [512][128] fp32 -> bf16, same layout; 16384-elem chunk
                const int base = (pid - 8) * 16384;
                for (int i = tid * 8; i < 16384; i += 2048) {
                    const float* s = a.wih + base + i;
                    f32x4 v0 = *(const f32x4*)s, v1 = *(const f32x4*)(s + 4);
                    short8 o;
#pragma unroll
                    for (int j = 0; j < 4; ++j) {
                        o[j] = (short)bf16_of(v0[j]);
                        o[4 + j] = (short)bf16_of(v1[j]);
                    }
                    *(short8*)(a.wihB + base + i) = o;
                }
            }
        }
    }
}

// ---------------------------------------------------------------------------
// 27-block lstm_pipe (R8-identical): 2-layer LSTM pipeline + fused MLP heads
// + in-kernel xw0 pack.
//  block 0 producer : layer-0 recurrence -> bf16 hbuf; flags[0] += 1/16 steps;
//                     waits flags[3+g] for xw0 pack groups (17 waits total)
//  block 1 helper   : xw1(chunk) = h0 @ Wih1^T + bias -> fp16 4-slot ring
//  block 2 consumer : layer-1 recurrence off ring -> bf16 out1b; flags[2]
//  blocks 3-10      : head workers: `no` head (bufH3) immediately; op/pa/sk
//                     per 128-row strip as flags[2] publishes chunks.
//  blocks 11-26     : xw0 pack workers (bf16 MFMA, fp16 store, o-rows *0.5).
// xw0/xw1 are fp16 (halved stream). Per-step barrier = lgkmcnt(0)-only
// waitcnt + s_barrier. Epilogue DIRECT sigmoid; o-gate rows pre-scaled 0.5.

struct HeadArgs {
    const unsigned short* W1T[4];
    const float* b1[4];
    const unsigned short* W2T[4];
    const float* b2[4];
    float* outp[4];       // op, pa, sk, no
};

__device__ __forceinline__ void lstm_epilogue(
    const f32x4 accs[4], f32x4 xv0, f32x4 xv1, float* cst, float* hv,
    bool lo, float selLo)
{
    float t0[4], t1[4];
#pragma unroll
    for (int i = 0; i < 4; ++i) {
        // P0 = zi (lo) | zf (hi);  P1 = zg (lo) | zo/2 (hi, pre-scaled rows)
        float P0 = (lo ? accs[0][i] : dpp_shr8(accs[1][i])) + xv0[i];
        float P1 = (lo ? accs[2][i] : dpp_shr8(accs[3][i])) + xv1[i];
        P1 = fmaxf(P1, -30.f);                       // keep exp2 finite
        t0[i] = frcp(1.f + fexp2(-1.44269504f * P0));   // sig(zi) | sig(zf)
        float u = fexp2(-2.88539008f * P1);
        t1[i] = (1.f - selLo * u) * frcp(1.f + u);      // tanh(zg) | sig(zo)
    }
    float c2[4], og[4];
#pragma unroll
    for (int i = 0; i < 4; ++i) {
        float ig = t0[i];             // lo lanes: sig(zi)
        float fg = dpp_shl8(t0[i]);   // lo lanes pull hi's sig(zf)
        float gg = t1[i];             // lo lanes: tanh(zg)
        og[i] = dpp_shl8(t1[i]);      // lo lanes pull hi's sig(zo)
        c2[i] = fg * cst[i] + ig * gg;
        cst[i] = c2[i];
    }
    float pc0 = lo ? c2[0] : dpp_shr8(c2[1]);
    float pc1 = lo ? c2[2] : dpp_shr8(c2[3]);
    pc0 = fmaxf(pc0, -30.f);
    pc1 = fmaxf(pc1, -30.f);
    float u0 = fexp2(-2.88539008f * pc0);
    float tc0 = (1.f - u0) * frcp(1.f + u0);
    float u1 = fexp2(-2.88539008f * pc1);
    float tc1 = (1.f - u1) * frcp(1.f + u1);
    float th[4] = {tc0, dpp_shl8(tc0), tc1, dpp_shl8(tc1)};
#pragma unroll
    for (int i = 0; i < 4; ++i) hv[i] = og[i] * th[i];
}

// SINK=0: bf16 hbuf [t*1024 + b*128 + h]; SINK=1: bf16 out1b [(t*8+b)*128 + h]
template <int SINK>
__device__ __forceinline__ void lstm_step(
    unsigned short* Hc, unsigned short* Hn, const short8 afr[4][4],
    f32x4 xv0, f32x4 xv1, float* cst, unsigned short* __restrict__ sink,
    int t, int col, int quad, int h4, int b)
{
    short8 bfr[4];
#pragma unroll
    for (int c = 0; c < 4; ++c)
        bfr[c] = *(const short8*)&Hc[col * 136 + c * 32 + quad * 8];
    f32x4 accs[4] = {};
#pragma unroll
    for (int c = 0; c < 4; ++c)
#pragma unroll
        for (int g = 0; g < 4; ++g)
            accs[g] = mfma16(afr[g][c], bfr[c], accs[g]);

    const bool lo = (col < 8);
    const float selLo = lo ? 1.f : 0.f;
    float hv[4];
    lstm_epilogue(accs, xv0, xv1, cst, hv, lo, selLo);
    if (lo) {
        u32x2 hb = {bf16pk(hv[0], hv[1]), bf16pk(hv[2], hv[3])};
        *(u32x2*)&Hn[b * 136 + h4] = hb;
        if (SINK == 0)
            *(u32x2*)(sink + (size_t)t * 1024 + b * 128 + h4) = hb;
        else
            *(u32x2*)(sink + ((size_t)t * 8 + b) * 128 + h4) = hb;
    }
    __builtin_amdgcn_s_waitcnt(0xC07F);  // lgkmcnt(0) only
    __builtin_amdgcn_s_barrier();
}

// One 128-row strip of a 2-layer MLP head (8 waves / 512 threads).
// A32=1: Asrc fp32 [row][128]; else bf16 [row][128].
// LROWS=1: global row r encodes (t=r>>3, b=r&7) -> out[(b*1024+t)*dout + n];
// else out[r*dout + n].
template <int A32, int LROWS>
__device__ void head_strip(
    const void* __restrict__ Asrc, int row0,
    const unsigned short* __restrict__ W1T, const float* __restrict__ b1,
    const unsigned short* __restrict__ W2T, const float* __restrict__ b2,
    float* __restrict__ outp, int dout, unsigned short* A2, int tid)
{
    const int lane = tid & 63, w = tid >> 6;
    const int quad = lane >> 4, col = lane & 15;
    const int mrow = w * 16 + col;          // A-frag row within strip
    // GEMM1: [128 x 128] @ W1T -> relu -> A2 (bf16)
    f32x4 acc[8] = {};
#pragma unroll
    for (int kc = 0; kc < 4; ++kc) {
        short8 af;
        if (A32) {
            const float* s = (const float*)Asrc + (size_t)(row0 + mrow) * 128 + kc * 32 + quad * 8;
            f32x4 v0 = *(const f32x4*)s, v1 = *(const f32x4*)(s + 4);
            short8 v;
#pragma unroll
            for (int j = 0; j < 4; ++j) {
                v[j] = (short)bf16_of(v0[j]);
                v[4 + j] = (short)bf16_of(v1[j]);
            }
            af = v;
        } else {
            af = *(const short8*)((const unsigned short*)Asrc +
                                  (size_t)(row0 + mrow) * 128 + kc * 32 + quad * 8);
        }
#pragma unroll
        for (int nt = 0; nt < 8; ++nt) {
            short8 bf = *(const short8*)&W1T[(nt * 16 + col) * 128 + kc * 32 + quad * 8];
            acc[nt] = mfma16(af, bf, acc[nt]);
        }
    }
    float b1v[8];
#pragma unroll
    for (int nt = 0; nt < 8; ++nt) b1v[nt] = b1[nt * 16 + col];
    __syncthreads();   // previous strip's A2 reads done
#pragma unroll
    for (int nt = 0; nt < 8; ++nt)
#pragma unroll
        for (int i = 0; i < 4; ++i) {
            const int mm = w * 16 + quad * 4 + i;
            A2[mm * 136 + nt * 16 + col] = bf16_of(fmaxf(acc[nt][i] + b1v[nt], 0.f));
        }
    __syncthreads();
    // GEMM2: A2 @ W2T -> out (+b2)
    const int ntiles = dout >> 4;
    for (int np = 0; np < ntiles; np += 8) {
        const int nts = (ntiles - np < 8) ? ntiles - np : 8;
        f32x4 acc2[8] = {};
#pragma unroll
        for (int kc = 0; kc < 4; ++kc) {
            short8 a2f = *(const short8*)&A2[mrow * 136 + kc * 32 + quad * 8];
            for (int nt = 0; nt < nts; ++nt) {
                short8 bf = *(const short8*)&W2T[((np + nt) * 16 + col) * 128 + kc * 32 + quad * 8];
                acc2[nt] = mfma16(a2f, bf, acc2[nt]);
            }
        }
        for (int nt = 0; nt < nts; ++nt) {
            const int n = (np + nt) * 16 + col;
            const float bb = b2[n];
#pragma unroll
            for (int i = 0; i < 4; ++i) {
                const int r = row0 + w * 16 + quad * 4 + i;
                size_t off;
                if (LROWS) off = ((size_t)(r & 7) * 1024 + (r >> 3)) * dout + n;
                else       off = (size_t)r * dout + n;
                outp[off] = acc2[nt][i] + bb;
            }
        }
    }
}

__global__ __launch_bounds__(512, 2) void lstm_pipe(
    const __half* __restrict__ xw0, const float* __restrict__ Whh0,
    const float* __restrict__ Wih1, const float* __restrict__ Whh1,
    const float* __restrict__ bih1, const float* __restrict__ bhh1,
    unsigned short* __restrict__ hbuf, __half* __restrict__ xw1,
    int* __restrict__ flags, unsigned short* __restrict__ out1b,
    const float* __restrict__ bufH3, HeadArgs ha,
    const float* __restrict__ bih0, const float* __restrict__ bhh0,
    const unsigned short* __restrict__ WihB)
{
    __shared__ __align__(16) unsigned short H[2][16 * 136];
    __shared__ __align__(16) unsigned short A2[128 * 136];
    const int tid = threadIdx.x;
    const int lane = tid & 63;
    const int w = tid >> 6;
    const int quad = lane >> 4;
    const int col = lane & 15;
    const int b = col & 7;
    const int prA = col >> 3;
    const int h4 = w * 16 + quad * 4;

    if (blockIdx.x >= 11) {
        // ---------------- xw0 pack workers (blocks 11-26) ----------------
        const int wid = blockIdx.x - 11;   // 0..15
        unsigned short* hA = A2;           // 64x136 bf16 staging (reuses A2)
        const float gsc = (w >= 6) ? 0.5f : 1.f;
        float bs[4];
#pragma unroll
        for (int nt = 0; nt < 4; ++nt) {
            const int n = w * 64 + nt * 16 + col;
            bs[nt] = bih0[n] + bhh0[n];
        }
        for (int idx = wid; idx < 128; idx += 16) {
            const int g = idx >> 3, bq = idx & 7;
            const int row0 = bq * 1024 + g * 64;
            {   // stage h3 64x128 fp32 -> bf16 LDS [64][136]
                const int r = tid >> 3, c0 = (tid & 7) * 16;
                const float* src = bufH3 + (size_t)(row0 + r) * 128 + c0;
                unsigned short* dst = hA + r * 136 + c0;
#pragma unroll
                for (int e = 0; e < 16; e += 8) {
                    f32x4 v0 = *(const f32x4*)(src + e);
                    f32x4 v1 = *(const f32x4*)(src + e + 4);
                    short8 o;
#pragma unroll
                    for (int j = 0; j < 4; ++j) {
                        o[j] = (short)bf16_of(v0[j]);
                        o[4 + j] = (short)bf16_of(v1[j]);
                    }
                    *(short8*)(dst + e) = o;
                }
            }
            __syncthreads();
#pragma unroll
            for (int rt = 0; rt < 4; ++rt) {
                short8 af[4];
#pragma unroll
                for (int c = 0; c < 4; ++c)
                    af[c] = *(const short8*)&hA[(rt * 16 + col) * 136 + c * 32 + quad * 8];
                f32x4 acc[4] = {};
#pragma unroll
                for (int c = 0; c < 4; ++c)
#pragma unroll
                    for (int nt = 0; nt < 4; ++nt) {
                        short8 bf = *(const short8*)&WihB[(size_t)(w * 64 + nt * 16 + col) * 128 + c * 32 + quad * 8];
                        acc[nt] = mfma16(af[c], bf, acc[nt]);
                    }
#pragma unroll
                for (int nt = 0; nt < 4; ++nt) {
                    const int pr = w >> 1;
                    const int h = (w & 1) * 64 + nt * 16 + col;
#pragma unroll
                    for (int i = 0; i < 4; ++i) {
                        const int t_ = g * 64 + rt * 16 + quad * 4 + i;
                        __half* dst = (__half*)xw0 +
                            (((size_t)t_ * 4 + pr) * 8 + bq) * 128 + h;
                        *dst = (__half)((acc[nt][i] + bs[nt]) * gsc);
                    }
                }
            }
            __builtin_amdgcn_s_waitcnt(0x0F70);  // vmcnt(0): own stores done
            __builtin_amdgcn_s_barrier();        // all waves' stores done; hA reusable
            if (tid == 0)
                __hip_atomic_fetch_add(&flags[3 + g], 1, __ATOMIC_RELEASE,
                                       __HIP_MEMORY_SCOPE_AGENT);
        }
        return;
    }

    if (blockIdx.x >= 3) {
        // ---------------- head workers ----------------
        const int wid = blockIdx.x - 3;   // 0..7
        for (int s = wid; s < 64; s += 8)
            head_strip<1, 0>(bufH3, s * 128, ha.W1T[3], ha.b1[3],
                             ha.W2T[3], ha.b2[3], ha.outp[3], 64, A2, tid);
        for (int s = wid; s < 64; s += 8) {
            if (tid == 0) {
                while (__hip_atomic_load(&flags[2], __ATOMIC_ACQUIRE,
                                         __HIP_MEMORY_SCOPE_AGENT) < s + 1)
                    __builtin_amdgcn_s_sleep(16);
            }
            __syncthreads();
            head_strip<0, 1>(out1b, s * 128, ha.W1T[0], ha.b1[0],
                             ha.W2T[0], ha.b2[0], ha.outp[0], 64, A2, tid);
            head_strip<0, 1>(out1b, s * 128, ha.W1T[1], ha.b1[1],
                             ha.W2T[1], ha.b2[1], ha.outp[1], 256, A2, tid);
            head_strip<0, 1>(out1b, s * 128, ha.W1T[2], ha.b1[2],
                             ha.W2T[2], ha.b2[2], ha.outp[2], 128, A2, tid);
        }
        return;
    }

    if (blockIdx.x == 1) {
        // ---------------- helper: xw1 = h0 @ Wih1^T + bias (fp16 out) ------
        short8 afrI[4][4];
        f32x4 biasv[4];
#pragma unroll
        for (int g = 0; g < 4; ++g) {
            const float gsc = (g == 3) ? 0.5f : 1.f;   // o-gate pre-scale
            const int row = g * 128 + w * 16 + col;
#pragma unroll
            for (int c = 0; c < 4; ++c) {
                const float* src = Wih1 + row * 128 + c * 32 + quad * 8;
                short8 v;
#pragma unroll
                for (int j = 0; j < 8; ++j) v[j] = (short)bf16_of(src[j] * gsc);
                afrI[g][c] = v;
            }
            const int rb = g * 128 + w * 16 + quad * 4;
            f32x4 b1 = *(const f32x4*)&bih1[rb];
            f32x4 b2 = *(const f32x4*)&bhh1[rb];
#pragma unroll
            for (int e = 0; e < 4; ++e) biasv[g][e] = (b1[e] + b2[e]) * gsc;
        }
        for (int k = 0; k < 64; ++k) {
            if (tid == 0) {
                while (__hip_atomic_load(&flags[0], __ATOMIC_ACQUIRE,
                                         __HIP_MEMORY_SCOPE_AGENT) < k + 1)
                    __builtin_amdgcn_s_sleep(2);
                if (k >= 4) {
                    while (__hip_atomic_load(&flags[2], __ATOMIC_RELAXED,
                                             __HIP_MEMORY_SCOPE_AGENT) < k - 3)
                        __builtin_amdgcn_s_sleep(2);
                }
            }
            __builtin_amdgcn_s_waitcnt(0xC07F);
            __builtin_amdgcn_s_barrier();
            const unsigned short* hb = hbuf + (size_t)k * 16 * 1024;
            __half* dst = xw1 + (size_t)(k & 3) * 65536;
#pragma unroll 2
            for (int nt = 0; nt < 8; ++nt) {
                const int tl = nt * 2 + (col >> 3);
                const unsigned short* src = hb + tl * 1024 + b * 128 + quad * 8;
                short8 bfr[4];
#pragma unroll
                for (int c = 0; c < 4; ++c) bfr[c] = *(const short8*)&src[c * 32];
                f32x4 acc[4] = {};
#pragma unroll
                for (int c = 0; c < 4; ++c)
#pragma unroll
                    for (int g = 0; g < 4; ++g)
                        acc[g] = mfma16(afrI[g][c], bfr[c], acc[g]);
#pragma unroll
                for (int g = 0; g < 4; ++g) {
                    u32x2 res = {fp16pk(acc[g][0] + biasv[g][0], acc[g][1] + biasv[g][1]),
                                 fp16pk(acc[g][2] + biasv[g][2], acc[g][3] + biasv[g][3])};
                    *(u32x2*)&dst[((tl * 4 + g) * 8 + b) * 128 + w * 16 + quad * 4] = res;
                }
            }
            __builtin_amdgcn_s_waitcnt(0x0F70);  // vmcnt(0) only
            __builtin_amdgcn_s_barrier();
            if (tid == 0)
                __hip_atomic_store(&flags[1], k + 1, __ATOMIC_RELEASE,
                                   __HIP_MEMORY_SCOPE_AGENT);
        }
        return;
    }

    for (int i = tid; i < 2 * 16 * 136; i += 512) (&H[0][0])[i] = 0;
    float cst[4] = {0.f, 0.f, 0.f, 0.f};
    const int lane_off = (prA * 8 + b) * 128 + h4;

    if (blockIdx.x == 0) {
        // ---------------- producer: layer 0 ----------------
        short8 afr[4][4];
#pragma unroll
        for (int g = 0; g < 4; ++g) {
            const float gsc = (g == 3) ? 0.5f : 1.f;   // o-gate pre-scale
            const int row = g * 128 + w * 16 + col;
#pragma unroll
            for (int c = 0; c < 4; ++c) {
                const float* src = Whh0 + row * 128 + c * 32 + quad * 8;
                short8 v;
#pragma unroll
                for (int j = 0; j < 8; ++j) v[j] = (short)bf16_of(src[j] * gsc);
                afr[g][c] = v;
            }
        }
        // wait for xw0 pack group 0 (t 0..63) before the initial prefetch
        if (tid == 0) {
            while (__hip_atomic_load(&flags[3], __ATOMIC_ACQUIRE,
                                     __HIP_MEMORY_SCOPE_AGENT) < 8)
                __builtin_amdgcn_s_sleep(2);
        }
        __syncthreads();
        const __half* xp = xw0 + lane_off;
        u32x2 p0a = *(const u32x2*)(xp);
        u32x2 p1a = *(const u32x2*)(xp + 2048);
        u32x2 p0b = *(const u32x2*)(xp + 4096);
        u32x2 p1b = *(const u32x2*)(xp + 6144);
        xp += 8192;
        __syncthreads();

        for (int t = 0; t < 1024; t += 2) {
            if ((t & 63) == 48) {   // loads in this stretch reach group (t>>6)+1
                const int gw = (t >> 6) + 1;
                if (gw < 16) {
                    if (tid == 0) {
                        while (__hip_atomic_load(&flags[3 + gw], __ATOMIC_ACQUIRE,
                                                 __HIP_MEMORY_SCOPE_AGENT) < 8)
                            __builtin_amdgcn_s_sleep(2);
                    }
                    __builtin_amdgcn_s_waitcnt(0xC07F);
                    __builtin_amdgcn_s_barrier();
                }
            }
            const __half* xr = (t == 1022) ? xp - 8192 : xp;
            {
                f32x4 xv0 = h4f(p0a), xv1 = h4f(p1a);
                p0a = *(const u32x2*)(xr);
                p1a = *(const u32x2*)(xr + 2048);
                lstm_step<0>(&H[0][0], &H[1][0], afr, xv0, xv1, cst, hbuf, t, col, quad, h4, b);
            }
            {
                f32x4 xv0 = h4f(p0b), xv1 = h4f(p1b);
                p0b = *(const u32x2*)(xr + 4096);
                p1b = *(const u32x2*)(xr + 6144);
                lstm_step<0>(&H[1][0], &H[0][0], afr, xv0, xv1, cst, hbuf, t + 1, col, quad, h4, b);
            }
            xp += 8192;
            if ((t & 14) == 14) {   // chunk (t>>4) complete
                __syncthreads();    // drain hbuf stores across the block
                if (tid == 0)
                    __hip_atomic_store(&flags[0], (t >> 4) + 1, __ATOMIC_RELEASE,
                                       __HIP_MEMORY_SCOPE_AGENT);
            }
        }
    } else {
        // ---------------- consumer: layer 1 ----------------
        short8 afr[4][4];
#pragma unroll
        for (int g = 0; g < 4; ++g) {
            const float gsc = (g == 3) ? 0.5f : 1.f;   // o-gate pre-scale
            const int row = g * 128 + w * 16 + col;
#pragma unroll
            for (int c = 0; c < 4; ++c) {
                const float* src = Whh1 + row * 128 + c * 32 + quad * 8;
                short8 v;
#pragma unroll
                for (int j = 0; j < 8; ++j) v[j] = (short)bf16_of(src[j] * gsc);
                afr[g][c] = v;
            }
        }
        __syncthreads();
        auto xaddr = [&](int t) -> const __half* {
            return xw1 + (((t >> 4) & 3) * 65536 + (t & 15) * 4096) + lane_off;
        };
        while (__hip_atomic_load(&flags[1], __ATOMIC_ACQUIRE,
                                 __HIP_MEMORY_SCOPE_AGENT) < 2)
            __builtin_amdgcn_s_sleep(2);
        u32x2 p0a = *(const u32x2*)xaddr(0);
        u32x2 p1a = *(const u32x2*)(xaddr(0) + 2048);
        u32x2 p0b = *(const u32x2*)xaddr(1);
        u32x2 p1b = *(const u32x2*)(xaddr(1) + 2048);

        for (int c = 0; c < 64; ++c) {
            if (c > 0) {
                const int target = (c + 2 < 64) ? c + 2 : 64;
                if (tid == 0) {
                    while (__hip_atomic_load(&flags[1], __ATOMIC_ACQUIRE,
                                             __HIP_MEMORY_SCOPE_AGENT) < target)
                        __builtin_amdgcn_s_sleep(2);
                }
                __builtin_amdgcn_s_waitcnt(0xC07F);
                __builtin_amdgcn_s_barrier();
            }
            for (int s = 0; s < 16; s += 2) {
                const int t = c * 16 + s;
                const int t2 = (t + 2 < 1024) ? t + 2 : 1023;
                const int t3 = (t + 3 < 1024) ? t + 3 : 1023;
                {
                    f32x4 xv0 = h4f(p0a), xv1 = h4f(p1a);
                    p0a = *(const u32x2*)xaddr(t2);
                    p1a = *(const u32x2*)(xaddr(t2) + 2048);
                    lstm_step<1>(&H[0][0], &H[1][0], afr, xv0, xv1, cst, out1b, t, col, quad, h4, b);
                }
                {
                    f32x4 xv0 = h4f(p0b), xv1 = h4f(p1b);
                    p0b = *(const u32x2*)xaddr(t3);
                    p1b = *(const u32x2*)(xaddr(t3) + 2048);
                    lstm_step<1>(&H[1][0], &H[0][0], afr, xv0, xv1, cst, out1b, t + 1, col, quad, h4, b);
                }
            }
            __syncthreads();   // drain out1b stores before publishing chunk
            if (tid == 0)
                __hip_atomic_store(&flags[2], c + 1, __ATOMIC_RELEASE,
                                   __HIP_MEMORY_SCOPE_AGENT);
        }
    }
}

// ---------------------------------------------------------------------------
extern "C" void kernel_launch(void* const* d_in, const int* in_sizes, int n_in,
                              void* d_out, int out_size, void* d_ws, size_t ws_size,
                              hipStream_t stream)
{
    (void)in_sizes; (void)n_in; (void)out_size; (void)ws_size;
    const float* nf    = (const float*)d_in[0];
    const float* adj   = (const float*)d_in[1];
    const float* g1W   = (const float*)d_in[3];
    const float* g1b   = (const float*)d_in[4];
    const float* g1aW  = (const float*)d_in[5];
    const float* g1ab  = (const float*)d_in[6];
    const float* g2W   = (const float*)d_in[7];
    const float* g2b   = (const float*)d_in[8];
    const float* g2aW  = (const float*)d_in[9];
    const float* g2ab  = (const float*)d_in[10];
    const float* g3W   = (const float*)d_in[11];
    const float* g3b   = (const float*)d_in[12];
    const float* g3aW  = (const float*)d_in[13];
    const float* g3ab  = (const float*)d_in[14];
    const float* l0Wih = (const float*)d_in[15];
    const float* l0Whh = (const float*)d_in[16];
    const float* l0bih = (const float*)d_in[17];
    const float* l0bhh = (const float*)d_in[18];
    const float* l1Wih = (const float*)d_in[19];
    const float* l1Whh = (const float*)d_in[20];
    const float* l1bih = (const float*)d_in[21];
    const float* l1bhh = (const float*)d_in[22];
    const float* opW1 = (const float*)d_in[23];
    const float* opb1 = (const float*)d_in[24];
    const float* opW2 = (const float*)d_in[25];
    const float* opb2 = (const float*)d_in[26];
    const float* paW1 = (const float*)d_in[27];
    const float* pab1 = (const float*)d_in[28];
    const float* paW2 = (const float*)d_in[29];
    const float* pab2 = (const float*)d_in[30];
    const float* skW1 = (const float*)d_in[31];
    const float* skb1 = (const float*)d_in[32];
    const float* skW2 = (const float*)d_in[33];
    const float* skb2 = (const float*)d_in[34];
    const float* noW1 = (const float*)d_in[35];
    const float* nob1 = (const float*)d_in[36];
    const float* noW2 = (const float*)d_in[37];
    const float* nob2 = (const float*)d_in[38];

    float* out = (float*)d_out;
    float* ws = (float*)d_ws;
    float* siP0  = ws;                       // [2][8192]
    float* sjP0  = ws + 16384;               // [2][8192]
    float* siP1  = ws + 32768;               // [2][8192]
    float* sjP1  = ws + 49152;               // [2][8192]
    unsigned short* WihB = (unsigned short*)(ws + 65536);    // 65536 shorts
    int*  gflags = (int*)(ws + 98304);       // 1024 ints (gnn + lstm flags)
    float* bufX  = ws + 1048576;             // gnn ping / later hbuf
    float* bufH3 = ws + 2097152;             // gnn3 out (node head input)
    unsigned short* bufT0 = (unsigned short*)(ws + 3145728); // hT layer 1/3
    float* xw0f = ws + 3687424;              // fp16: 4194304 halfs (8 MB)
    float* xw1f = ws + 7881728;              // fp16 ring: 262144 halfs (512 KB)
    unsigned short* WT = (unsigned short*)(ws + 8143876);    // 131072 shorts
    unsigned short* out1b = (unsigned short*)(ws + 8209412); // 1048576 shorts
    unsigned short* hbuf = (unsigned short*)bufX;            // 2 MB
    __half* xw0 = (__half*)xw0f;
    __half* xw1 = (__half*)xw1f;
    // hT layer 2 aliases the xw0 region (xw0 is written only inside
    // lstm_pipe's pack workers, after the GNN phases are done).
    unsigned short* bufT1 = (unsigned short*)xw0f;
    int* lflags = gflags + 544;              // lstm flags [0..19)

    unsigned short* opW1T = WT;
    unsigned short* paW1T = WT + 16384;
    unsigned short* skW1T = WT + 32768;
    unsigned short* noW1T = WT + 49152;
    unsigned short* opW2T = WT + 65536;
    unsigned short* paW2T = WT + 73728;
    unsigned short* skW2T = WT + 106496;
    unsigned short* noW2T = WT + 122880;

    GnnArgs ga;
    ga.nf = nf; ga.adj = adj;
    ga.gW0 = g1W; ga.gb0 = g1b; ga.gaW0 = g1aW; ga.gab0 = g1ab;
    ga.gW1 = g2W; ga.gb1 = g2b; ga.gaW1 = g2aW; ga.gab1 = g2ab;
    ga.gW2 = g3W; ga.gb2 = g3b; ga.gaW2 = g3aW; ga.gab2 = g3ab;
    ga.bufX = bufX; ga.bufH3 = bufH3;
    ga.hT0 = bufT0; ga.hT1 = bufT1;
    ga.siP0 = siP0; ga.sjP0 = sjP0; ga.siP1 = siP1; ga.sjP1 = sjP1;
    ga.gf = gflags;
    ga.wih = l0Wih; ga.wihB = WihB;
    ga.prep.src[0] = opW1; ga.prep.dst[0] = opW1T; ga.prep.N[0] = 128;
    ga.prep.src[1] = paW1; ga.prep.dst[1] = paW1T; ga.prep.N[1] = 128;
    ga.prep.src[2] = skW1; ga.prep.dst[2] = skW1T; ga.prep.N[2] = 128;
    ga.prep.src[3] = noW1; ga.prep.dst[3] = noW1T; ga.prep.N[3] = 128;
    ga.prep.src[4] = opW2; ga.prep.dst[4] = opW2T; ga.prep.N[4] = 64;
    ga.prep.src[5] = paW2; ga.prep.dst[5] = paW2T; ga.prep.N[5] = 256;
    ga.prep.src[6] = skW2; ga.prep.dst[6] = skW2T; ga.prep.N[6] = 128;
    ga.prep.src[7] = noW2; ga.prep.dst[7] = noW2T; ga.prep.N[7] = 64;

    // zero all flags (gnn tile flags + lstm flags) — graph-capture-legal async
    hipMemsetAsync(gflags, 0, 4096, stream);

    // ---- fused GNN front-end: 2 launches, per-tile flag dependencies
    gnn_fused<<<1280, 256, 0, stream>>>(ga, 0);   // gemm1 | agg1 | gemm2
    gnn_fused<<<1036, 256, 0, stream>>>(ga, 1);   // agg2 | gemm3 | agg3 | prep

    // ---- pipelined LSTM + fused heads + in-kernel xw0 pack
    HeadArgs ha;
    ha.W1T[0] = opW1T; ha.b1[0] = opb1; ha.W2T[0] = opW2T; ha.b2[0] = opb2;
    ha.outp[0] = out + 0;
    ha.W1T[1] = paW1T; ha.b1[1] = pab1; ha.W2T[1] = paW2T; ha.b2[1] = pab2;
    ha.outp[1] = out + 524288;
    ha.W1T[2] = skW1T; ha.b1[2] = skb1; ha.W2T[2] = skW2T; ha.b2[2] = skb2;
    ha.outp[2] = out + 2621440;
    ha.W1T[3] = noW1T; ha.b1[3] = nob1; ha.W2T[3] = noW2T; ha.b2[3] = nob2;
    ha.outp[3] = out + 3670016;
    lstm_pipe<<<27, 512, 0, stream>>>(xw0, l0Whh, l1Wih, l1Whh, l1bih, l1bhh,
                                      hbuf, xw1, lflags, out1b, bufH3, ha,
                                      l0bih, l0bhh, WihB);
}

// Round 10
// 1308.762 us; speedup vs baseline: 1.2973x; 1.2973x over previous
//
#include <hip/hip_runtime.h>
#include <hip/hip_fp16.h>

typedef __attribute__((ext_vector_type(8))) short short8;
typedef __attribute__((ext_vector_type(4))) float f32x4;
typedef __attribute__((ext_vector_type(2))) unsigned int u32x2;

__device__ __forceinline__ unsigned short bf16_of(float f) {
    unsigned u = __builtin_bit_cast(unsigned, f);
    u += 0x7fffu + ((u >> 16) & 1u);   // RNE
    return (unsigned short)(u >> 16);
}
__device__ __forceinline__ unsigned bf16pk(float a, float b) {
    return (unsigned)bf16_of(a) | ((unsigned)bf16_of(b) << 16);
}
// fp16 pack (RTZ) / unpack for the xw streams.
__device__ __forceinline__ unsigned fp16pk(float a, float b) {
    return __builtin_bit_cast(unsigned, __builtin_amdgcn_cvt_pkrtz(a, b));
}
__device__ __forceinline__ f32x4 h4f(u32x2 v) {
    __half2 a = __builtin_bit_cast(__half2, v[0]);
    __half2 b = __builtin_bit_cast(__half2, v[1]);
    float2 fa = __half22float2(a), fb = __half22float2(b);
    f32x4 r; r[0] = fa.x; r[1] = fa.y; r[2] = fb.x; r[3] = fb.y;
    return r;
}
__device__ __forceinline__ float fexp2(float x) { return __builtin_amdgcn_exp2f(x); }
__device__ __forceinline__ float frcp(float x) { return __builtin_amdgcn_rcpf(x); }
__device__ __forceinline__ float sigm(float x) { return frcp(1.f + fexp2(-1.44269504f * x)); }
__device__ __forceinline__ f32x4 mfma16(short8 a, short8 b, f32x4 c) {
    return __builtin_amdgcn_mfma_f32_16x16x32_bf16(a, b, c, 0, 0, 0);
}
// DPP cross-lane within 16-lane rows. row_shr:8 -> lane i gets lane i-8;
// row_shl:8 -> lane i gets lane i+8 (bound_ctrl: OOB reads 0).
__device__ __forceinline__ float dpp_shr8(float x) {
    return __builtin_bit_cast(float, __builtin_amdgcn_update_dpp(
        0, __builtin_bit_cast(int, x), 0x118, 0xF, 0xF, true));
}
__device__ __forceinline__ float dpp_shl8(float x) {
    return __builtin_bit_cast(float, __builtin_amdgcn_update_dpp(
        0, __builtin_bit_cast(int, x), 0x108, 0xF, 0xF, true));
}

struct PrepArgs {
    const float* src[8];
    unsigned short* dst[8];
    int N[8];
};

// ---------------------------------------------------------------------------
// Fused GNN linear: h = A @ W + b (fp32, N=128 fixed), emitting
//   - hT[b][d][node] = bf16(h)          (MFMA B staging for gnn_agg)
//   - siP/sjP partial attention dots    (per 64-col block; summed in gnn_agg)
// 32-row M-tiles (grid 2 x 256 = 512 blocks -> 2 blocks/CU for latency
// hiding). Blocks with blockIdx.y >= 256 (first launch only) run prep:
// head-weight transposes, flag zeroing (19 flags), l0Wih -> bf16 WihB.
__global__ __launch_bounds__(256) void gemm_gnn(
    const float* __restrict__ A, const float* __restrict__ B,
    const float* __restrict__ bias, const float* __restrict__ aW,
    unsigned short* __restrict__ hT, float* __restrict__ siP,
    float* __restrict__ sjP, int K,
    PrepArgs pa, const float* __restrict__ wih,
    unsigned short* __restrict__ wihB, int* __restrict__ flags)
{
    const int tid = threadIdx.x;
    if (blockIdx.y >= 256) {
        // ---- prep tail blocks (first launch only) ----
        const int pid = (blockIdx.y - 256) * 2 + blockIdx.x;
        if (pid < 8) {
            const float* src = pa.src[pid];
            unsigned short* dst = pa.dst[pid];
            const int N = pa.N[pid];
            const int n0 = tid >> 4, kc = (tid & 15) * 8;
            for (int n = n0; n < N; n += 16) {
                unsigned o[4];
#pragma unroll
                for (int e = 0; e < 8; e += 2)
                    o[e >> 1] = bf16pk(src[(size_t)(kc + e) * N + n],
                                       src[(size_t)(kc + e + 1) * N + n]);
                *(u32x2*)&dst[n * 128 + kc] = *(u32x2*)&o[0];
                *(u32x2*)&dst[n * 128 + kc + 4] = *(u32x2*)&o[2];
            }
        } else if (pid == 8) {
            if (tid < 19) flags[tid] = 0;
        } else if (pid < 13) {
            // l0Wih [512][128] fp32 -> bf16, same layout; chunk of 16384
            const int base = (pid - 9) * 16384;
            for (int i = tid * 8; i < 16384; i += 2048) {
                const float* s = wih + base + i;
                f32x4 v0 = *(const f32x4*)s, v1 = *(const f32x4*)(s + 4);
                short8 o;
#pragma unroll
                for (int j = 0; j < 4; ++j) {
                    o[j] = (short)bf16_of(v0[j]);
                    o[4 + j] = (short)bf16_of(v1[j]);
                }
                *(short8*)(wihB + base + i) = o;
            }
        }
        return;
    }

    __shared__ float As[32][33];
    __shared__ float Bs[32][68];
    __shared__ unsigned short T[32][70];   // [node_local][d_local] bf16
    const int tx = tid & 15, ty = tid >> 4;
    const int m0 = blockIdx.y * 32, n0 = blockIdx.x * 64;
    float acc[2][4];
#pragma unroll
    for (int i = 0; i < 2; ++i)
#pragma unroll
        for (int j = 0; j < 4; ++j) acc[i][j] = 0.f;

    for (int k0 = 0; k0 < K; k0 += 32) {
        __syncthreads();
        {   // stage A 32x32
            const int r = tid >> 3, kk = (tid & 7) * 4;
            f32x4 v = *(const f32x4*)(A + (size_t)(m0 + r) * K + k0 + kk);
#pragma unroll
            for (int e = 0; e < 4; ++e) As[r][kk + e] = v[e];
        }
        {   // stage B 32x64 (B is [K][128])
            const int kk = tid >> 3, nn = (tid & 7) * 8;
            const float* src = B + (size_t)(k0 + kk) * 128 + n0 + nn;
            f32x4 v0 = *(const f32x4*)src;
            f32x4 v1 = *(const f32x4*)(src + 4);
#pragma unroll
            for (int e = 0; e < 4; ++e) { Bs[kk][nn + e] = v0[e]; Bs[kk][nn + 4 + e] = v1[e]; }
        }
        __syncthreads();
#pragma unroll 8
        for (int k = 0; k < 32; ++k) {
            float a0 = As[ty * 2 + 0][k], a1 = As[ty * 2 + 1][k];
            f32x4 bv = *(const f32x4*)&Bs[k][tx * 4];
#pragma unroll
            for (int j = 0; j < 4; ++j) {
                acc[0][j] += a0 * bv[j];
                acc[1][j] += a1 * bv[j];
            }
        }
    }
    // bias
    f32x4 bv = *(const f32x4*)&bias[n0 + tx * 4];
#pragma unroll
    for (int i = 0; i < 2; ++i)
#pragma unroll
        for (int j = 0; j < 4; ++j) acc[i][j] += bv[j];

    // si/sj partial dots: per row m, partial over this block's 64 cols.
    f32x4 wj = *(const f32x4*)&aW[n0 + tx * 4];
    f32x4 wi = *(const f32x4*)&aW[128 + n0 + tx * 4];
#pragma unroll
    for (int i = 0; i < 2; ++i) {
        float pj = acc[i][0] * wj[0] + acc[i][1] * wj[1] + acc[i][2] * wj[2] + acc[i][3] * wj[3];
        float pi = acc[i][0] * wi[0] + acc[i][1] * wi[1] + acc[i][2] * wi[2] + acc[i][3] * wi[3];
#pragma unroll
        for (int o = 8; o > 0; o >>= 1) {
            pj += __shfl_xor(pj, o);
            pi += __shfl_xor(pi, o);
        }
        if (tx == 0) {
            const int m = m0 + ty * 2 + i;
            sjP[blockIdx.x * 8192 + m] = pj;
            siP[blockIdx.x * 8192 + m] = pi;
        }
    }

    // bf16 transpose via LDS -> hT[b][n0+d][node]
#pragma unroll
    for (int i = 0; i < 2; ++i) {
        unsigned* tp = (unsigned*)&T[ty * 2 + i][tx * 4];
        tp[0] = bf16pk(acc[i][0], acc[i][1]);
        tp[1] = bf16pk(acc[i][2], acc[i][3]);
    }
    __syncthreads();
    const int b = m0 >> 10, node0 = m0 & 1023;
    const int dr = tid >> 4, npair = tid & 15;
#pragma unroll
    for (int rr = 0; rr < 4; ++rr) {
        const int d = rr * 16 + dr;
        unsigned o = (unsigned)T[npair * 2][d] | ((unsigned)T[npair * 2 + 1][d] << 16);
        *(unsigned*)(hT + ((size_t)b * 128 + n0 + d) * 1024 + node0 + npair * 2) = o;
    }
}

// ---------------------------------------------------------------------------
// out[b,i,d] = sum_j sigmoid(si[i]+sj[j]+ab)*adj[b,i,j]*h[b,j,d]  (opt relu)
// 32-row i-tiles (grid 32x8 = 256 blocks), depth-2 register prefetch of
// adj/hT so HBM latency hides under the previous tile's stage+MFMA.
__global__ __launch_bounds__(256) void gnn_agg(
    const float* __restrict__ adj, const unsigned short* __restrict__ hT,
    const float* __restrict__ siP, const float* __restrict__ sjP,
    const float* __restrict__ abp, float* __restrict__ out, int RELU)
{
    __shared__ __align__(16) unsigned short Alds[32 * 40];   // [i][j] stride 40
    __shared__ __align__(16) unsigned short Blds[128 * 40];  // [d][j] stride 40
    __shared__ float sjL[1024];
    const int b = blockIdx.y, it = blockIdx.x;
    const int i0 = it * 32;
    const int tid = threadIdx.x, lane = tid & 63, w = tid >> 6;
    const int quad = lane >> 4, col = lane & 15;
    const int rh = w & 1, nh = w >> 1;   // wave -> (i-half, d-half)
    const float ab = abp[0];
    const float* adjb = adj + (size_t)b * 1024 * 1024;
    const unsigned short* hTb = hT + (size_t)b * 128 * 1024;

    for (int j = tid; j < 1024; j += 256)
        sjL[j] = sjP[b * 1024 + j] + sjP[8192 + b * 1024 + j];

    const int ar_ = tid >> 3, ash = (tid & 7) * 4;   // A-stage: 32 rows x 8 thr x 4 j
    const int br_ = tid >> 1, bsh = (tid & 1) * 16;  // B-stage: 128 rows x 2 thr x 16 j
    const float sii = siP[b * 1024 + i0 + ar_] + siP[8192 + b * 1024 + i0 + ar_] + ab;

    const float* aptr = adjb + (size_t)(i0 + ar_) * 1024 + ash;
    const unsigned short* bptr = hTb + (size_t)br_ * 1024 + bsh;

    f32x4 paA = *(const f32x4*)(aptr);
    short8 pbA0 = *(const short8*)(bptr);
    short8 pbA1 = *(const short8*)(bptr + 8);
    f32x4 paB = *(const f32x4*)(aptr + 32);
    short8 pbB0 = *(const short8*)(bptr + 32);
    short8 pbB1 = *(const short8*)(bptr + 40);

    f32x4 acc[4] = {};

    for (int j0 = 0; j0 < 1024; j0 += 64) {
        // ---- phase A: tile j0
        __syncthreads();
        {
            float s0 = sigm(sii + sjL[j0 + ash + 0]) * paA[0];
            float s1 = sigm(sii + sjL[j0 + ash + 1]) * paA[1];
            float s2 = sigm(sii + sjL[j0 + ash + 2]) * paA[2];
            float s3 = sigm(sii + sjL[j0 + ash + 3]) * paA[3];
            u32x2 o = {bf16pk(s0, s1), bf16pk(s2, s3)};
            *(u32x2*)&Alds[ar_ * 40 + ash] = o;
            *(short8*)&Blds[br_ * 40 + bsh] = pbA0;
            *(short8*)&Blds[br_ * 40 + bsh + 8] = pbA1;
        }
        if (j0 + 64 < 1024) {
            paA = *(const f32x4*)(aptr + j0 + 64);
            pbA0 = *(const short8*)(bptr + j0 + 64);
            pbA1 = *(const short8*)(bptr + j0 + 72);
        }
        __syncthreads();
        {
            short8 af = *(const short8*)&Alds[(rh * 16 + col) * 40 + quad * 8];
#pragma unroll
            for (int nt = 0; nt < 4; ++nt) {
                short8 bf = *(const short8*)&Blds[((nh * 4 + nt) * 16 + col) * 40 + quad * 8];
                acc[nt] = mfma16(af, bf, acc[nt]);
            }
        }
        // ---- phase B: tile j0+32
        __syncthreads();
        {
            float s0 = sigm(sii + sjL[j0 + 32 + ash + 0]) * paB[0];
            float s1 = sigm(sii + sjL[j0 + 32 + ash + 1]) * paB[1];
            float s2 = sigm(sii + sjL[j0 + 32 + ash + 2]) * paB[2];
            float s3 = sigm(sii + sjL[j0 + 32 + ash + 3]) * paB[3];
            u32x2 o = {bf16pk(s0, s1), bf16pk(s2, s3)};
            *(u32x2*)&Alds[ar_ * 40 + ash] = o;
            *(short8*)&Blds[br_ * 40 + bsh] = pbB0;
            *(short8*)&Blds[br_ * 40 + bsh + 8] = pbB1;
        }
        if (j0 + 96 < 1024) {
            paB = *(const f32x4*)(aptr + j0 + 96);
            pbB0 = *(const short8*)(bptr + j0 + 96);
            pbB1 = *(const short8*)(bptr + j0 + 104);
        }
        __syncthreads();
        {
            short8 af = *(const short8*)&Alds[(rh * 16 + col) * 40 + quad * 8];
#pragma unroll
            for (int nt = 0; nt < 4; ++nt) {
                short8 bf = *(const short8*)&Blds[((nh * 4 + nt) * 16 + col) * 40 + quad * 8];
                acc[nt] = mfma16(af, bf, acc[nt]);
            }
        }
    }
    const int ibase = i0 + rh * 16 + quad * 4;
#pragma unroll
    for (int nt = 0; nt < 4; ++nt) {
        const int d = (nh * 4 + nt) * 16 + col;
#pragma unroll
        for (int r = 0; r < 4; ++r) {
            float v = acc[nt][r];
            if (RELU) v = fmaxf(v, 0.f);
            out[((size_t)b * 1024 + ibase + r) * 128 + d] = v;
        }
    }
}

// ---------------------------------------------------------------------------
// 27-block lstm_pipe: 2-layer LSTM pipeline + fused MLP heads + in-kernel
// xw0 pack.
//  block 0 producer : layer-0 recurrence -> bf16 hbuf; flags[0] += 1/16 steps;
//                     waits flags[3+g] for xw0 pack groups (17 waits total)
//  block 1 helper   : xw1(chunk) = h0 @ Wih1^T + bias -> fp16 4-slot ring
//  block 2 consumer : layer-1 recurrence off ring -> bf16 out1b; flags[2]
//  blocks 3-10      : head workers: `no` head (bufH3) immediately; op/pa/sk
//                     per 128-row strip as flags[2] publishes chunks.
//  blocks 11-26     : xw0 pack workers: tile (b, t-range-64) via bf16 MFMA
//                     (h3 @ WihB^T + bih+bhh, o-rows *0.5, fp16 store) in
//                     t-group-major order; atomicAdd(&flags[3+g]) (release,
//                     agent) after vmcnt(0)+barrier. Replaces the serial
//                     pack-GEMM dispatch: runs on otherwise-idle CUs and
//                     stays ~20x ahead of the producer's 67 us/group pace.
// xw0/xw1 are fp16 (halved stream). Per-step barrier = lgkmcnt(0)-only
// waitcnt + s_barrier. Epilogue DIRECT sigmoid; o-gate rows pre-scaled 0.5.

struct HeadArgs {
    const unsigned short* W1T[4];
    const float* b1[4];
    const unsigned short* W2T[4];
    const float* b2[4];
    float* outp[4];       // op, pa, sk, no
};

__device__ __forceinline__ void lstm_epilogue(
    const f32x4 accs[4], f32x4 xv0, f32x4 xv1, float* cst, float* hv,
    bool lo, float selLo)
{
    float t0[4], t1[4];
#pragma unroll
    for (int i = 0; i < 4; ++i) {
        // P0 = zi (lo) | zf (hi);  P1 = zg (lo) | zo/2 (hi, pre-scaled rows)
        float P0 = (lo ? accs[0][i] : dpp_shr8(accs[1][i])) + xv0[i];
        float P1 = (lo ? accs[2][i] : dpp_shr8(accs[3][i])) + xv1[i];
        P1 = fmaxf(P1, -30.f);                       // keep exp2 finite
        t0[i] = frcp(1.f + fexp2(-1.44269504f * P0));   // sig(zi) | sig(zf)
        float u = fexp2(-2.88539008f * P1);
        t1[i] = (1.f - selLo * u) * frcp(1.f + u);      // tanh(zg) | sig(zo)
    }
    float c2[4], og[4];
#pragma unroll
    for (int i = 0; i < 4; ++i) {
        float ig = t0[i];             // lo lanes: sig(zi)
        float fg = dpp_shl8(t0[i]);   // lo lanes pull hi's sig(zf)
        float gg = t1[i];             // lo lanes: tanh(zg)
        og[i] = dpp_shl8(t1[i]);      // lo lanes pull hi's sig(zo)
        c2[i] = fg * cst[i] + ig * gg;
        cst[i] = c2[i];
    }
    float pc0 = lo ? c2[0] : dpp_shr8(c2[1]);
    float pc1 = lo ? c2[2] : dpp_shr8(c2[3]);
    pc0 = fmaxf(pc0, -30.f);
    pc1 = fmaxf(pc1, -30.f);
    float u0 = fexp2(-2.88539008f * pc0);
    float tc0 = (1.f - u0) * frcp(1.f + u0);
    float u1 = fexp2(-2.88539008f * pc1);
    float tc1 = (1.f - u1) * frcp(1.f + u1);
    float th[4] = {tc0, dpp_shl8(tc0), tc1, dpp_shl8(tc1)};
#pragma unroll
    for (int i = 0; i < 4; ++i) hv[i] = og[i] * th[i];
}

// SINK=0: bf16 hbuf [t*1024 + b*128 + h]; SINK=1: bf16 out1b [(t*8+b)*128 + h]
template <int SINK>
__device__ __forceinline__ void lstm_step(
    unsigned short* Hc, unsigned short* Hn, const short8 afr[4][4],
    f32x4 xv0, f32x4 xv1, float* cst, unsigned short* __restrict__ sink,
    int t, int col, int quad, int h4, int b)
{
    short8 bfr[4];
#pragma unroll
    for (int c = 0; c < 4; ++c)
        bfr[c] = *(const short8*)&Hc[col * 136 + c * 32 + quad * 8];
    f32x4 accs[4] = {};
#pragma unroll
    for (int c = 0; c < 4; ++c)
#pragma unroll
        for (int g = 0; g < 4; ++g)
            accs[g] = mfma16(afr[g][c], bfr[c], accs[g]);

    const bool lo = (col < 8);
    const float selLo = lo ? 1.f : 0.f;
    float hv[4];
    lstm_epilogue(accs, xv0, xv1, cst, hv, lo, selLo);
    if (lo) {
        u32x2 hb = {bf16pk(hv[0], hv[1]), bf16pk(hv[2], hv[3])};
        *(u32x2*)&Hn[b * 136 + h4] = hb;
        if (SINK == 0)
            *(u32x2*)(sink + (size_t)t * 1024 + b * 128 + h4) = hb;
        else
            *(u32x2*)(sink + ((size_t)t * 8 + b) * 128 + h4) = hb;
    }
    __builtin_amdgcn_s_waitcnt(0xC07F);  // lgkmcnt(0) only
    __builtin_amdgcn_s_barrier();
}

// One 128-row strip of a 2-layer MLP head (8 waves / 512 threads).
// A32=1: Asrc fp32 [row][128]; else bf16 [row][128].
// LROWS=1: global row r encodes (t=r>>3, b=r&7) -> out[(b*1024+t)*dout + n];
// else out[r*dout + n].
template <int A32, int LROWS>
__device__ void head_strip(
    const void* __restrict__ Asrc, int row0,
    const unsigned short* __restrict__ W1T, const float* __restrict__ b1,
    const unsigned short* __restrict__ W2T, const float* __restrict__ b2,
    float* __restrict__ outp, int dout, unsigned short* A2, int tid)
{
    const int lane = tid & 63, w = tid >> 6;
    const int quad = lane >> 4, col = lane & 15;
    const int mrow = w * 16 + col;          // A-frag row within strip
    // GEMM1: [128 x 128] @ W1T -> relu -> A2 (bf16)
    f32x4 acc[8] = {};
#pragma unroll
    for (int kc = 0; kc < 4; ++kc) {
        short8 af;
        if (A32) {
            const float* s = (const float*)Asrc + (size_t)(row0 + mrow) * 128 + kc * 32 + quad * 8;
            f32x4 v0 = *(const f32x4*)s, v1 = *(const f32x4*)(s + 4);
            short8 v;
#pragma unroll
            for (int j = 0; j < 4; ++j) {
                v[j] = (short)bf16_of(v0[j]);
                v[4 + j] = (short)bf16_of(v1[j]);
            }
            af = v;
        } else {
            af = *(const short8*)((const unsigned short*)Asrc +
                                  (size_t)(row0 + mrow) * 128 + kc * 32 + quad * 8);
        }
#pragma unroll
        for (int nt = 0; nt < 8; ++nt) {
            short8 bf = *(const short8*)&W1T[(nt * 16 + col) * 128 + kc * 32 + quad * 8];
            acc[nt] = mfma16(af, bf, acc[nt]);
        }
    }
    float b1v[8];
#pragma unroll
    for (int nt = 0; nt < 8; ++nt) b1v[nt] = b1[nt * 16 + col];
    __syncthreads();   // previous strip's A2 reads done
#pragma unroll
    for (int nt = 0; nt < 8; ++nt)
#pragma unroll
        for (int i = 0; i < 4; ++i) {
            const int mm = w * 16 + quad * 4 + i;
            A2[mm * 136 + nt * 16 + col] = bf16_of(fmaxf(acc[nt][i] + b1v[nt], 0.f));
        }
    __syncthreads();
    // GEMM2: A2 @ W2T -> out (+b2)
    const int ntiles = dout >> 4;
    for (int np = 0; np < ntiles; np += 8) {
        const int nts = (ntiles - np < 8) ? ntiles - np : 8;
        f32x4 acc2[8] = {};
#pragma unroll
        for (int kc = 0; kc < 4; ++kc) {
            short8 a2f = *(const short8*)&A2[mrow * 136 + kc * 32 + quad * 8];
            for (int nt = 0; nt < nts; ++nt) {
                short8 bf = *(const short8*)&W2T[((np + nt) * 16 + col) * 128 + kc * 32 + quad * 8];
                acc2[nt] = mfma16(a2f, bf, acc2[nt]);
            }
        }
        for (int nt = 0; nt < nts; ++nt) {
            const int n = (np + nt) * 16 + col;
            const float bb = b2[n];
#pragma unroll
            for (int i = 0; i < 4; ++i) {
                const int r = row0 + w * 16 + quad * 4 + i;
                size_t off;
                if (LROWS) off = ((size_t)(r & 7) * 1024 + (r >> 3)) * dout + n;
                else       off = (size_t)r * dout + n;
                outp[off] = acc2[nt][i] + bb;
            }
        }
    }
}

__global__ __launch_bounds__(512, 2) void lstm_pipe(
    const __half* __restrict__ xw0, const float* __restrict__ Whh0,
    const float* __restrict__ Wih1, const float* __restrict__ Whh1,
    const float* __restrict__ bih1, const float* __restrict__ bhh1,
    unsigned short* __restrict__ hbuf, __half* __restrict__ xw1,
    int* __restrict__ flags, unsigned short* __restrict__ out1b,
    const float* __restrict__ bufH3, HeadArgs ha,
    const float* __restrict__ bih0, const float* __restrict__ bhh0,
    const unsigned short* __restrict__ WihB)
{
    __shared__ __align__(16) unsigned short H[2][16 * 136];
    __shared__ __align__(16) unsigned short A2[128 * 136];
    const int tid = threadIdx.x;
    const int lane = tid & 63;
    const int w = tid >> 6;
    const int quad = lane >> 4;
    const int col = lane & 15;
    const int b = col & 7;
    const int prA = col >> 3;
    const int h4 = w * 16 + quad * 4;

    if (blockIdx.x >= 11) {
        // ---------------- xw0 pack workers (blocks 11-26) ----------------
        const int wid = blockIdx.x - 11;   // 0..15
        unsigned short* hA = A2;           // 64x136 bf16 staging (reuses A2)
        const float gsc = (w >= 6) ? 0.5f : 1.f;
        float bs[4];
#pragma unroll
        for (int nt = 0; nt < 4; ++nt) {
            const int n = w * 64 + nt * 16 + col;
            bs[nt] = bih0[n] + bhh0[n];
        }
        for (int idx = wid; idx < 128; idx += 16) {
            const int g = idx >> 3, bq = idx & 7;
            const int row0 = bq * 1024 + g * 64;
            {   // stage h3 64x128 fp32 -> bf16 LDS [64][136]
                const int r = tid >> 3, c0 = (tid & 7) * 16;
                const float* src = bufH3 + (size_t)(row0 + r) * 128 + c0;
                unsigned short* dst = hA + r * 136 + c0;
#pragma unroll
                for (int e = 0; e < 16; e += 8) {
                    f32x4 v0 = *(const f32x4*)(src + e);
                    f32x4 v1 = *(const f32x4*)(src + e + 4);
                    short8 o;
#pragma unroll
                    for (int j = 0; j < 4; ++j) {
                        o[j] = (short)bf16_of(v0[j]);
                        o[4 + j] = (short)bf16_of(v1[j]);
                    }
                    *(short8*)(dst + e) = o;
                }
            }
            __syncthreads();
#pragma unroll
            for (int rt = 0; rt < 4; ++rt) {
                short8 af[4];
#pragma unroll
                for (int c = 0; c < 4; ++c)
                    af[c] = *(const short8*)&hA[(rt * 16 + col) * 136 + c * 32 + quad * 8];
                f32x4 acc[4] = {};
#pragma unroll
                for (int c = 0; c < 4; ++c)
#pragma unroll
                    for (int nt = 0; nt < 4; ++nt) {
                        short8 bf = *(const short8*)&WihB[(size_t)(w * 64 + nt * 16 + col) * 128 + c * 32 + quad * 8];
                        acc[nt] = mfma16(af[c], bf, acc[nt]);
                    }
#pragma unroll
                for (int nt = 0; nt < 4; ++nt) {
                    const int pr = w >> 1;
                    const int h = (w & 1) * 64 + nt * 16 + col;
#pragma unroll
                    for (int i = 0; i < 4; ++i) {
                        const int t_ = g * 64 + rt * 16 + quad * 4 + i;
                        __half* dst = (__half*)xw0 +
                            (((size_t)t_ * 4 + pr) * 8 + bq) * 128 + h;
                        *dst = (__half)((acc[nt][i] + bs[nt]) * gsc);
                    }
                }
            }
            __builtin_amdgcn_s_waitcnt(0x0F70);  // vmcnt(0): own stores done
            __builtin_amdgcn_s_barrier();        // all waves' stores done; hA reusable
            if (tid == 0)
                __hip_atomic_fetch_add(&flags[3 + g], 1, __ATOMIC_RELEASE,
                                       __HIP_MEMORY_SCOPE_AGENT);
        }
        return;
    }

    if (blockIdx.x >= 3) {
        // ---------------- head workers ----------------
        const int wid = blockIdx.x - 3;   // 0..7
        for (int s = wid; s < 64; s += 8)
            head_strip<1, 0>(bufH3, s * 128, ha.W1T[3], ha.b1[3],
                             ha.W2T[3], ha.b2[3], ha.outp[3], 64, A2, tid);
        for (int s = wid; s < 64; s += 8) {
            if (tid == 0) {
                while (__hip_atomic_load(&flags[2], __ATOMIC_ACQUIRE,
                                         __HIP_MEMORY_SCOPE_AGENT) < s + 1)
                    __builtin_amdgcn_s_sleep(16);
            }
            __syncthreads();
            head_strip<0, 1>(out1b, s * 128, ha.W1T[0], ha.b1[0],
                             ha.W2T[0], ha.b2[0], ha.outp[0], 64, A2, tid);
            head_strip<0, 1>(out1b, s * 128, ha.W1T[1], ha.b1[1],
                             ha.W2T[1], ha.b2[1], ha.outp[1], 256, A2, tid);
            head_strip<0, 1>(out1b, s * 128, ha.W1T[2], ha.b1[2],
                             ha.W2T[2], ha.b2[2], ha.outp[2], 128, A2, tid);
        }
        return;
    }

    if (blockIdx.x == 1) {
        // ---------------- helper: xw1 = h0 @ Wih1^T + bias (fp16 out) ------
        short8 afrI[4][4];
        f32x4 biasv[4];
#pragma unroll
        for (int g = 0; g < 4; ++g) {
            const float gsc = (g == 3) ? 0.5f : 1.f;   // o-gate pre-scale
            const int row = g * 128 + w * 16 + col;
#pragma unroll
            for (int c = 0; c < 4; ++c) {
                const float* src = Wih1 + row * 128 + c * 32 + quad * 8;
                short8 v;
#pragma unroll
                for (int j = 0; j < 8; ++j) v[j] = (short)bf16_of(src[j] * gsc);
                afrI[g][c] = v;
            }
            const int rb = g * 128 + w * 16 + quad * 4;
            f32x4 b1 = *(const f32x4*)&bih1[rb];
            f32x4 b2 = *(const f32x4*)&bhh1[rb];
#pragma unroll
            for (int e = 0; e < 4; ++e) biasv[g][e] = (b1[e] + b2[e]) * gsc;
        }
        for (int k = 0; k < 64; ++k) {
            if (tid == 0) {
                while (__hip_atomic_load(&flags[0], __ATOMIC_ACQUIRE,
                                         __HIP_MEMORY_SCOPE_AGENT) < k + 1)
                    __builtin_amdgcn_s_sleep(2);
                if (k >= 4) {
                    while (__hip_atomic_load(&flags[2], __ATOMIC_RELAXED,
                                             __HIP_MEMORY_SCOPE_AGENT) < k - 3)
                        __builtin_amdgcn_s_sleep(2);
                }
            }
            __builtin_amdgcn_s_waitcnt(0xC07F);
            __builtin_amdgcn_s_barrier();
            const unsigned short* hb = hbuf + (size_t)k * 16 * 1024;
            __half* dst = xw1 + (size_t)(k & 3) * 65536;
#pragma unroll 2
            for (int nt = 0; nt < 8; ++nt) {
                const int tl = nt * 2 + (col >> 3);
                const unsigned short* src = hb + tl * 1024 + b * 128 + quad * 8;
                short8 bfr[4];
#pragma unroll
                for (int c = 0; c < 4; ++c) bfr[c] = *(const short8*)&src[c * 32];
                f32x4 acc[4] = {};
#pragma unroll
                for (int c = 0; c < 4; ++c)
#pragma unroll
                    for (int g = 0; g < 4; ++g)
                        acc[g] = mfma16(afrI[g][c], bfr[c], acc[g]);
#pragma unroll
                for (int g = 0; g < 4; ++g) {
                    u32x2 res = {fp16pk(acc[g][0] + biasv[g][0], acc[g][1] + biasv[g][1]),
                                 fp16pk(acc[g][2] + biasv[g][2], acc[g][3] + biasv[g][3])};
                    *(u32x2*)&dst[((tl * 4 + g) * 8 + b) * 128 + w * 16 + quad * 4] = res;
                }
            }
            __builtin_amdgcn_s_waitcnt(0x0F70);  // vmcnt(0) only
            __builtin_amdgcn_s_barrier();
            if (tid == 0)
                __hip_atomic_store(&flags[1], k + 1, __ATOMIC_RELEASE,
                                   __HIP_MEMORY_SCOPE_AGENT);
        }
        return;
    }

    for (int i = tid; i < 2 * 16 * 136; i += 512) (&H[0][0])[i] = 0;
    float cst[4] = {0.f, 0.f, 0.f, 0.f};
    const int lane_off = (prA * 8 + b) * 128 + h4;

    if (blockIdx.x == 0) {
        // ---------------- producer: layer 0 ----------------
        short8 afr[4][4];
#pragma unroll
        for (int g = 0; g < 4; ++g) {
            const float gsc = (g == 3) ? 0.5f : 1.f;   // o-gate pre-scale
            const int row = g * 128 + w * 16 + col;
#pragma unroll
            for (int c = 0; c < 4; ++c) {
                const float* src = Whh0 + row * 128 + c * 32 + quad * 8;
                short8 v;
#pragma unroll
                for (int j = 0; j < 8; ++j) v[j] = (short)bf16_of(src[j] * gsc);
                afr[g][c] = v;
            }
        }
        // wait for xw0 pack group 0 (t 0..63) before the initial prefetch
        if (tid == 0) {
            while (__hip_atomic_load(&flags[3], __ATOMIC_ACQUIRE,
                                     __HIP_MEMORY_SCOPE_AGENT) < 8)
                __builtin_amdgcn_s_sleep(2);
        }
        __syncthreads();
        const __half* xp = xw0 + lane_off;
        u32x2 p0a = *(const u32x2*)(xp);
        u32x2 p1a = *(const u32x2*)(xp + 2048);
        u32x2 p0b = *(const u32x2*)(xp + 4096);
        u32x2 p1b = *(const u32x2*)(xp + 6144);
        xp += 8192;
        __syncthreads();

        for (int t = 0; t < 1024; t += 2) {
            if ((t & 63) == 48) {   // loads in this stretch reach group (t>>6)+1
                const int gw = (t >> 6) + 1;
                if (gw < 16) {
                    if (tid == 0) {
                        while (__hip_atomic_load(&flags[3 + gw], __ATOMIC_ACQUIRE,
                                                 __HIP_MEMORY_SCOPE_AGENT) < 8)
                            __builtin_amdgcn_s_sleep(2);
                    }
                    __builtin_amdgcn_s_waitcnt(0xC07F);
                    __builtin_amdgcn_s_barrier();
                }
            }
            const __half* xr = (t == 1022) ? xp - 8192 : xp;
            {
                f32x4 xv0 = h4f(p0a), xv1 = h4f(p1a);
                p0a = *(const u32x2*)(xr);
                p1a = *(const u32x2*)(xr + 2048);
                lstm_step<0>(&H[0][0], &H[1][0], afr, xv0, xv1, cst, hbuf, t, col, quad, h4, b);
            }
            {
                f32x4 xv0 = h4f(p0b), xv1 = h4f(p1b);
                p0b = *(const u32x2*)(xr + 4096);
                p1b = *(const u32x2*)(xr + 6144);
                lstm_step<0>(&H[1][0], &H[0][0], afr, xv0, xv1, cst, hbuf, t + 1, col, quad, h4, b);
            }
            xp += 8192;
            if ((t & 14) == 14) {   // chunk (t>>4) complete
                __syncthreads();    // drain hbuf stores across the block
                if (tid == 0)
                    __hip_atomic_store(&flags[0], (t >> 4) + 1, __ATOMIC_RELEASE,
                                       __HIP_MEMORY_SCOPE_AGENT);
            }
        }
    } else {
        // ---------------- consumer: layer 1 ----------------
        short8 afr[4][4];
#pragma unroll
        for (int g = 0; g < 4; ++g) {
            const float gsc = (g == 3) ? 0.5f : 1.f;   // o-gate pre-scale
            const int row = g * 128 + w * 16 + col;
#pragma unroll
            for (int c = 0; c < 4; ++c) {
                const float* src = Whh1 + row * 128 + c * 32 + quad * 8;
                short8 v;
#pragma unroll
                for (int j = 0; j < 8; ++j) v[j] = (short)bf16_of(src[j] * gsc);
                afr[g][c] = v;
            }
        }
        __syncthreads();
        auto xaddr = [&](int t) -> const __half* {
            return xw1 + (((t >> 4) & 3) * 65536 + (t & 15) * 4096) + lane_off;
        };
        while (__hip_atomic_load(&flags[1], __ATOMIC_ACQUIRE,
                                 __HIP_MEMORY_SCOPE_AGENT) < 2)
            __builtin_amdgcn_s_sleep(2);
        u32x2 p0a = *(const u32x2*)xaddr(0);
        u32x2 p1a = *(const u32x2*)(xaddr(0) + 2048);
        u32x2 p0b = *(const u32x2*)xaddr(1);
        u32x2 p1b = *(const u32x2*)(xaddr(1) + 2048);

        for (int c = 0; c < 64; ++c) {
            if (c > 0) {
                const int target = (c + 2 < 64) ? c + 2 : 64;
                if (tid == 0) {
                    while (__hip_atomic_load(&flags[1], __ATOMIC_ACQUIRE,
                                             __HIP_MEMORY_SCOPE_AGENT) < target)
                        __builtin_amdgcn_s_sleep(2);
                }
                __builtin_amdgcn_s_waitcnt(0xC07F);
                __builtin_amdgcn_s_barrier();
            }
            for (int s = 0; s < 16; s += 2) {
                const int t = c * 16 + s;
                const int t2 = (t + 2 < 1024) ? t + 2 : 1023;
                const int t3 = (t + 3 < 1024) ? t + 3 : 1023;
                {
                    f32x4 xv0 = h4f(p0a), xv1 = h4f(p1a);
                    p0a = *(const u32x2*)xaddr(t2);
                    p1a = *(const u32x2*)(xaddr(t2) + 2048);
                    lstm_step<1>(&H[0][0], &H[1][0], afr, xv0, xv1, cst, out1b, t, col, quad, h4, b);
                }
                {
                    f32x4 xv0 = h4f(p0b), xv1 = h4f(p1b);
                    p0b = *(const u32x2*)xaddr(t3);
                    p1b = *(const u32x2*)(xaddr(t3) + 2048);
                    lstm_step<1>(&H[1][0], &H[0][0], afr, xv0, xv1, cst, out1b, t + 1, col, quad, h4, b);
                }
            }
            __syncthreads();   // drain out1b stores before publishing chunk
            if (tid == 0)
                __hip_atomic_store(&flags[2], c + 1, __ATOMIC_RELEASE,
                                   __HIP_MEMORY_SCOPE_AGENT);
        }
    }
}

// ---------------------------------------------------------------------------
extern "C" void kernel_launch(void* const* d_in, const int* in_sizes, int n_in,
                              void* d_out, int out_size, void* d_ws, size_t ws_size,
                              hipStream_t stream)
{
    (void)in_sizes; (void)n_in; (void)out_size; (void)ws_size;
    const float* nf    = (const float*)d_in[0];
    const float* adj   = (const float*)d_in[1];
    const float* g1W   = (const float*)d_in[3];
    const float* g1b   = (const float*)d_in[4];
    const float* g1aW  = (const float*)d_in[5];
    const float* g1ab  = (const float*)d_in[6];
    const float* g2W   = (const float*)d_in[7];
    const float* g2b   = (const float*)d_in[8];
    const float* g2aW  = (const float*)d_in[9];
    const float* g2ab  = (const float*)d_in[10];
    const float* g3W   = (const float*)d_in[11];
    const float* g3b   = (const float*)d_in[12];
    const float* g3aW  = (const float*)d_in[13];
    const float* g3ab  = (const float*)d_in[14];
    const float* l0Wih = (const float*)d_in[15];
    const float* l0Whh = (const float*)d_in[16];
    const float* l0bih = (const float*)d_in[17];
    const float* l0bhh = (const float*)d_in[18];
    const float* l1Wih = (const float*)d_in[19];
    const float* l1Whh = (const float*)d_in[20];
    const float* l1bih = (const float*)d_in[21];
    const float* l1bhh = (const float*)d_in[22];
    const float* opW1 = (const float*)d_in[23];
    const float* opb1 = (const float*)d_in[24];
    const float* opW2 = (const float*)d_in[25];
    const float* opb2 = (const float*)d_in[26];
    const float* paW1 = (const float*)d_in[27];
    const float* pab1 = (const float*)d_in[28];
    const float* paW2 = (const float*)d_in[29];
    const float* pab2 = (const float*)d_in[30];
    const float* skW1 = (const float*)d_in[31];
    const float* skb1 = (const float*)d_in[32];
    const float* skW2 = (const float*)d_in[33];
    const float* skb2 = (const float*)d_in[34];
    const float* noW1 = (const float*)d_in[35];
    const float* nob1 = (const float*)d_in[36];
    const float* noW2 = (const float*)d_in[37];
    const float* nob2 = (const float*)d_in[38];

    float* out = (float*)d_out;
    float* ws = (float*)d_ws;
    float* siP   = ws;                       // [2][8192]
    float* sjP   = ws + 16384;               // [2][8192]
    unsigned short* WihB = (unsigned short*)(ws + 40960);    // 65536 shorts
    float* bufX  = ws + 1048576;             // gnn ping / later hbuf
    float* bufH3 = ws + 2097152;             // gnn3 out (node head input)
    unsigned short* bufT = (unsigned short*)(ws + 3145728);  // hT -> 3670016
    int*  flags = (int*)(ws + 3686400);      // 19 ints (retired bsum slot)
    float* xw0f = ws + 3687424;              // fp16: 4194304 halfs (8 MB)
    float* xw1f = ws + 7881728;              // fp16 ring: 262144 halfs (512 KB)
    unsigned short* WT = (unsigned short*)(ws + 8143876);    // 131072 shorts
    unsigned short* out1b = (unsigned short*)(ws + 8209412); // 1048576 shorts
    unsigned short* hbuf = (unsigned short*)bufX;            // 2 MB
    __half* xw0 = (__half*)xw0f;
    __half* xw1 = (__half*)xw1f;

    unsigned short* opW1T = WT;
    unsigned short* paW1T = WT + 16384;
    unsigned short* skW1T = WT + 32768;
    unsigned short* noW1T = WT + 49152;
    unsigned short* opW2T = WT + 65536;
    unsigned short* paW2T = WT + 73728;
    unsigned short* skW2T = WT + 106496;
    unsigned short* noW2T = WT + 122880;

    PrepArgs pargs;
    pargs.src[0] = opW1; pargs.dst[0] = opW1T; pargs.N[0] = 128;
    pargs.src[1] = paW1; pargs.dst[1] = paW1T; pargs.N[1] = 128;
    pargs.src[2] = skW1; pargs.dst[2] = skW1T; pargs.N[2] = 128;
    pargs.src[3] = noW1; pargs.dst[3] = noW1T; pargs.N[3] = 128;
    pargs.src[4] = opW2; pargs.dst[4] = opW2T; pargs.N[4] = 64;
    pargs.src[5] = paW2; pargs.dst[5] = paW2T; pargs.N[5] = 256;
    pargs.src[6] = skW2; pargs.dst[6] = skW2T; pargs.N[6] = 128;
    pargs.src[7] = noW2; pargs.dst[7] = noW2T; pargs.N[7] = 64;

    // ---- GNN layer 1 (din=64, relu); prep rides along as by>=256 blocks
    gemm_gnn<<<dim3(2, 263), 256, 0, stream>>>(nf, g1W, g1b, g1aW, bufT, siP, sjP, 64,
                                               pargs, l0Wih, WihB, flags);
    gnn_agg<<<dim3(32, 8), 256, 0, stream>>>(adj, bufT, siP, sjP, g1ab, bufX, 1);
    // ---- GNN layer 2 (relu)
    gemm_gnn<<<dim3(2, 256), 256, 0, stream>>>(bufX, g2W, g2b, g2aW, bufT, siP, sjP, 128,
                                               pargs, l0Wih, WihB, flags);
    gnn_agg<<<dim3(32, 8), 256, 0, stream>>>(adj, bufT, siP, sjP, g2ab, bufX, 1);
    // ---- GNN layer 3 (no relu) -> bufH3
    gemm_gnn<<<dim3(2, 256), 256, 0, stream>>>(bufX, g3W, g3b, g3aW, bufT, siP, sjP, 128,
                                               pargs, l0Wih, WihB, flags);
    gnn_agg<<<dim3(32, 8), 256, 0, stream>>>(adj, bufT, siP, sjP, g3ab, bufH3, 0);

    // ---- pipelined LSTM + fused heads + in-kernel xw0 pack
    HeadArgs ha;
    ha.W1T[0] = opW1T; ha.b1[0] = opb1; ha.W2T[0] = opW2T; ha.b2[0] = opb2;
    ha.outp[0] = out + 0;
    ha.W1T[1] = paW1T; ha.b1[1] = pab1; ha.W2T[1] = paW2T; ha.b2[1] = pab2;
    ha.outp[1] = out + 524288;
    ha.W1T[2] = skW1T; ha.b1[2] = skb1; ha.W2T[2] = skW2T; ha.b2[2] = skb2;
    ha.outp[2] = out + 2621440;
    ha.W1T[3] = noW1T; ha.b1[3] = nob1; ha.W2T[3] = noW2T; ha.b2[3] = nob2;
    ha.outp[3] = out + 3670016;
    lstm_pipe<<<27, 512, 0, stream>>>(xw0, l0Whh, l1Wih, l1Whh, l1bih, l1bhh,
                                      hbuf, xw1, flags, out1b, bufH3, ha,
                                      l0bih, l0bhh, WihB);
}